// Round 12
// baseline (316.391 us; speedup 1.0000x reference)
//
#include <hip/hip_runtime.h>
#include <hip/hip_bf16.h>

#define CIN   256
#define COUT  32
#define IMG_H 96
#define IMG_W 96
#define HW    (IMG_H*IMG_W)
#define NB    2
#define NV    4
#define VSZ   64
#define NVOX  (VSZ*VSZ*VSZ)
#define TCH   32

typedef __attribute__((ext_vector_type(2))) float f32x2;

__device__ __forceinline__ float fast_exp2(float x) {
    float r;
    asm("v_exp_f32 %0, %1" : "=v"(r) : "v"(x));
    return r;
}

// async global->LDS DMA, 16 B per lane (m97 width). LDS dest wave-uniform;
// HW writes dest + lane*16. Global src per-lane.
__device__ __forceinline__ void gload_lds16(const float* g, float* l) {
    __builtin_amdgcn_global_load_lds(
        (const __attribute__((address_space(1))) void*)g,
        (__attribute__((address_space(3))) void*)l, 16, 0, 0);
}

// Kernel 1 (R16): 1x1 conv as LDS-tiled GEMM.
// Cross-variant invariant found: R6/R14 both plateau at ~10.5 B/cy/CU of
// VMEM return (capability ~60) with compute:load <= 16:1 on strided
// 256-512B granules -- the wave's life is the thin strided read stream,
// however buffered (R7/R8/R12/R13/R14/R15 all null/worse). This is the
// canonical-GEMM structure never tried: K-tiled [32ch x 64px] LDS tiles,
// staged ONCE per block via global_load_lds width=16 (R9 used width 4 +
// per-wave redundancy) as contiguous 1KB granules; inner loop = 512 fmac
// per 2 stage instrs (256:1). og x2 -> redundancy gone. T3-minimal
// schedule: STAGE(next) -> compute(cur) -> barrier; 1024cy FMA/tile
// covers ~500cy load latency.
__global__ __launch_bounds__(128, 4) void conv1x1_kernel(
    const float* __restrict__ features,   // [B,V,CIN,H,W] fp32
    const float* __restrict__ Wp,         // [COUT,CIN]
    const float* __restrict__ bp,         // [COUT]
    __hip_bfloat16* __restrict__ out)     // [B,V,H,W,COUT] bf16
{
    __shared__ float tile[2][TCH][64];             // 16 KB dbuf
    const int og   = __builtin_amdgcn_readfirstlane((threadIdx.x >> 6) & 1);
    const int lane = threadIdx.x & 63;
    const int bv   = blockIdx.y;
    const int px0  = blockIdx.x*64;
    const float* fb    = features + (size_t)bv*CIN*HW + px0;
    const float* wbase = Wp + (size_t)og*16*CIN;   // uniform -> scalar path

    // prologue: stage tile 0 (wave og stages rows og*16..og*16+15;
    // each issue = 1024 B = 4 contiguous 256 B channel-rows)
    #pragma unroll
    for (int i = 0; i < 4; ++i)
        gload_lds16(fb + (size_t)(og*16 + i*4 + (lane>>4))*HW + (lane&15)*4,
                    &tile[0][og*16 + i*4][0]);
    __syncthreads();                               // vmcnt drained by compiler

    float acc[16];
    #pragma unroll
    for (int j = 0; j < 16; ++j) acc[j] = 0.f;

    #pragma unroll
    for (int t = 0; t < CIN/TCH; ++t) {            // 8 K-tiles
        const int cur = t & 1;
        if (t + 1 < CIN/TCH) {                     // stage next tile first
            #pragma unroll
            for (int i = 0; i < 4; ++i)
                gload_lds16(fb + (size_t)((t+1)*TCH + og*16 + i*4 + (lane>>4))*HW
                               + (lane&15)*4,
                            &tile[cur^1][og*16 + i*4][0]);
        }
        #pragma unroll
        for (int c = 0; c < TCH; ++c) {            // 512 fmac vs 4 stage instrs
            const float x = tile[cur][c][lane];    // 2 lanes/bank: free
            #pragma unroll
            for (int j = 0; j < 16; ++j)           // 16 indep acc chains
                acc[j] += x * wbase[(size_t)j*CIN + t*TCH + c];
        }
        __syncthreads();                           // reads done + next staged
    }

    union { uint4 u4[2]; __hip_bfloat16 h[16]; } pk;
    #pragma unroll
    for (int j = 0; j < 16; ++j)
        pk.h[j] = __float2bfloat16(acc[j] + bp[og*16 + j]);
    __hip_bfloat16* op = out + ((size_t)(bv*HW + px0 + lane))*COUT + og*16;
    *(uint4*)(op)     = pk.u4[0];
    *(uint4*)(op + 8) = pk.u4[1];
}

// Kernel 2 (unchanged = R6 structure, best measured ~43us): voxel-per-
// lane, chunk-major, depth-1 view prefetch. R10 frustum-skip refuted;
// R12 depth-2 pipeline refuted (L2 thrash); R15 confirmed keep-as-is.
__global__ __launch_bounds__(256, 4) void volgen_kernel(
    const __hip_bfloat16* __restrict__ feats,  // [B,V,H,W,COUT] bf16
    const float* __restrict__ proj,            // [B,V,3,4]
    const float* __restrict__ coords,          // [B,NVOX,3]
    float* __restrict__ out)                   // [B,COUT,NVOX]
{
    const int tid = threadIdx.x;
    const int b   = blockIdx.y;
    const int n   = blockIdx.x*256 + tid;

    const float* cp = coords + ((size_t)b*NVOX + n)*3;
    const float X = cp[0], Y = cp[1], Z = cp[2];

    const float LOG2E = 1.4426950408889634f;

    int   off[NV][4];                          // byte offsets into feats
    float wgt[NV][4];                          // bilinear weight * log2(e)
    #pragma unroll
    for (int v = 0; v < NV; ++v) {
        const float* P = proj + (size_t)(b*NV + v)*12;   // uniform -> scalar
        const float wz = P[8]*X + P[9]*Y + P[10]*Z + P[11];
        const bool  vz = wz > 0.f;
        const float rz = __builtin_amdgcn_rcpf(wz);
        float px = (P[0]*X + P[1]*Y + P[2]*Z + P[3]) * rz * (95.f/96.f);
        float py = (P[4]*X + P[5]*Y + P[6]*Z + P[7]) * rz * (95.f/96.f);
        px = vz ? px : 0.f;  py = vz ? py : 0.f;
        px = fminf(fmaxf(px, -1.0e6f), 1.0e6f);
        py = fminf(fmaxf(py, -1.0e6f), 1.0e6f);
        const float fx0 = floorf(px), fy0 = floorf(py);
        const int x0 = (int)fx0, y0 = (int)fy0, x1 = x0+1, y1 = y0+1;
        const float wx1 = px - fx0, wx0 = 1.f - wx1;
        const float wy1 = py - fy0, wy0 = 1.f - wy1;
        const bool vx0 = (unsigned)x0 < (unsigned)IMG_W;
        const bool vx1 = (unsigned)x1 < (unsigned)IMG_W;
        const bool vy0 = (unsigned)y0 < (unsigned)IMG_H;
        const bool vy1 = (unsigned)y1 < (unsigned)IMG_H;
        const int cx0 = min(max(x0, 0), IMG_W-1), cx1 = min(max(x1, 0), IMG_W-1);
        const int cy0 = min(max(y0, 0), IMG_H-1), cy1 = min(max(y1, 0), IMG_H-1);
        const int base = ((b*NV + v)*HW)*COUT*2;         // bytes, uniform
        off[v][0] = base + (cy0*IMG_W + cx0)*(COUT*2);  wgt[v][0] = (vz & vx0 & vy0) ? wx0*wy0*LOG2E : 0.f;
        off[v][1] = base + (cy0*IMG_W + cx1)*(COUT*2);  wgt[v][1] = (vz & vx1 & vy0) ? wx1*wy0*LOG2E : 0.f;
        off[v][2] = base + (cy1*IMG_W + cx0)*(COUT*2);  wgt[v][2] = (vz & vx0 & vy1) ? wx0*wy1*LOG2E : 0.f;
        off[v][3] = base + (cy1*IMG_W + cx1)*(COUT*2);  wgt[v][3] = (vz & vx1 & vy1) ? wx1*wy1*LOG2E : 0.f;
    }

    const char* fb = (const char*)feats;
    const size_t ob = (size_t)b*COUT*NVOX + n;
    const float LN2 = 0.6931471805599453f;

    for (int ch0 = 0; ch0 < COUT; ch0 += 8) {
        f32x2 A2[4], B2[4];
        uint4 t[4], tn[4];

        #pragma unroll
        for (int c = 0; c < 4; ++c)                     // prime the pipeline
            t[c] = *(const uint4*)(fb + off[0][c] + ch0*2);

        #pragma unroll
        for (int v = 0; v < NV; ++v) {
            if (v < NV-1) {
                #pragma unroll
                for (int c = 0; c < 4; ++c)             // prefetch next view
                    tn[c] = *(const uint4*)(fb + off[v+1][c] + ch0*2);
            }

            f32x2 s2[4];
            #pragma unroll
            for (int c = 0; c < 4; ++c) {
                const float w = wgt[v][c];
                const f32x2 w2 = { w, w };
                const unsigned tu[4] = { t[c].x, t[c].y, t[c].z, t[c].w };
                #pragma unroll
                for (int k = 0; k < 4; ++k) {           // packed fma: 2 ch/instr
                    f32x2 f2;
                    f2.x = __uint_as_float(tu[k] << 16);
                    f2.y = __uint_as_float(tu[k] & 0xffff0000u);
                    if (c == 0) s2[k] = w2 * f2;        // no zero-init
                    else        s2[k] += w2 * f2;
                }
            }

            #pragma unroll
            for (int k = 0; k < 4; ++k) {
                f32x2 e2;
                e2.x = fast_exp2(s2[k].x);              // wgt pre-scaled: 2^s' = e^s
                e2.y = fast_exp2(s2[k].y);
                if (v == 0) { A2[k] = e2;  B2[k] = s2[k]*e2; }
                else        { A2[k] += e2; B2[k] += s2[k]*e2; }
            }

            if (v < NV-1) {
                #pragma unroll
                for (int c = 0; c < 4; ++c) t[c] = tn[c];   // rotate
            }
        }

        #pragma unroll
        for (int k = 0; k < 4; ++k) {                   // coalesced stores
            out[ob + (size_t)(ch0 + 2*k    )*NVOX] = B2[k].x * __builtin_amdgcn_rcpf(A2[k].x) * LN2;
            out[ob + (size_t)(ch0 + 2*k + 1)*NVOX] = B2[k].y * __builtin_amdgcn_rcpf(A2[k].y) * LN2;
        }
    }
}

extern "C" void kernel_launch(void* const* d_in, const int* in_sizes, int n_in,
                              void* d_out, int out_size, void* d_ws, size_t ws_size,
                              hipStream_t stream)
{
    const float* features = (const float*)d_in[0];   // [2,4,256,96,96]
    const float* proj     = (const float*)d_in[1];   // [2,4,3,4]
    const float* coords   = (const float*)d_in[2];   // [2,64,64,64,3]
    const float* Wp       = (const float*)d_in[3];   // [32,256]
    const float* bp       = (const float*)d_in[4];   // [32]
    float* out = (float*)d_out;                      // [2,32,64,64,64]
    __hip_bfloat16* featsT = (__hip_bfloat16*)d_ws;  // [2,4,96,96,32] bf16 = 4.72 MB

    hipLaunchKernelGGL(conv1x1_kernel, dim3(HW/64, NB*NV), dim3(128), 0, stream,
                       features, Wp, bp, featsT);
    hipLaunchKernelGGL(volgen_kernel, dim3(NVOX/256, NB), dim3(256), 0, stream,
                       featsT, proj, coords, out);
}

// Round 13
// 208.906 us; speedup vs baseline: 1.5145x; 1.5145x over previous
//
#include <hip/hip_runtime.h>
#include <hip/hip_bf16.h>

#define CIN   256
#define COUT  32
#define IMG_H 96
#define IMG_W 96
#define HW    (IMG_H*IMG_W)
#define NB    2
#define NV    4
#define VSZ   64
#define NVOX  (VSZ*VSZ*VSZ)

typedef __attribute__((ext_vector_type(2))) float f32x2;

__device__ __forceinline__ float fast_exp2(float x) {
    float r;
    asm("v_exp_f32 %0, %1" : "=v"(r) : "v"(x));
    return r;
}

// Kernel 1 (R17 = R6 verbatim, FINAL): 1x1 conv -> channel-last bf16.
// Eight structural variants tried (R7-R16): VGPR dbuf x2, LDS staging x2,
// CIN-split, K-split waves, float2+pkfma, LDS-weight broadcast, canonical
// global_load_lds GEMM -- every axis (MLP, occupancy, traffic, instr
// width, weight path, staging) null or worse. 44.7us with VGPR 16 /
// 18 waves/CU is this op's source-level floor on gfx950. DO NOT TOUCH.
__global__ __launch_bounds__(256) void conv1x1_kernel(
    const float* __restrict__ features,   // [B,V,CIN,H,W] fp32
    const float* __restrict__ Wp,         // [COUT,CIN]
    const float* __restrict__ bp,         // [COUT]
    __hip_bfloat16* __restrict__ out)     // [B,V,H,W,COUT] bf16
{
    const int og   = __builtin_amdgcn_readfirstlane((threadIdx.x >> 6) & 3);
    const int lane = threadIdx.x & 63;
    const int bv   = blockIdx.y;
    const int px   = blockIdx.x*64 + lane;
    const float* f     = features + (size_t)bv*CIN*HW + px;
    const float* wbase = Wp + (size_t)og*8*CIN;     // uniform -> scalar base

    float acc[8];
    #pragma unroll
    for (int j = 0; j < 8; ++j) acc[j] = bp[og*8 + j];   // uniform -> s_load

    for (int cc = 0; cc < CIN; cc += 8) {
        float x[8];
        #pragma unroll
        for (int i = 0; i < 8; ++i)                  // 8 indep coalesced loads
            x[i] = f[(size_t)(cc + i)*HW];
        #pragma unroll
        for (int i = 0; i < 8; ++i) {
            #pragma unroll
            for (int j = 0; j < 8; ++j)              // v_fmac v, s, v
                acc[j] += x[i] * wbase[(size_t)j*CIN + cc + i];
        }
    }

    union { uint4 u4; __hip_bfloat16 h[8]; } pk;
    #pragma unroll
    for (int j = 0; j < 8; ++j) pk.h[j] = __float2bfloat16(acc[j]);
    *(uint4*)(out + ((size_t)(bv*HW + px))*COUT + og*8) = pk.u4;
}

// Kernel 2 (R17): VIEW-PER-LANE volgen. Quad lane v owns view v of one
// voxel (64 voxels/block). vs voxel-per-lane (43us, VALUBusy 45%,
// latency-bound): projection chain 232->58 ops (4x parallel), all 16
// chunk gathers issue concurrently from 4 lanes, exp/lane 32->8. A,B
// combined by 2-step __shfl_xor quad butterfly; lane q stores channels
// ch0+2q (64B-contiguous per channel across quads). Dynamic-index spill
// (rule #20) avoided via cndmask selects. Chunks walk +16B in the same
// 64B corner lines -> reuse distance stays short (no R12 thrash mode).
__global__ __launch_bounds__(256, 4) void volgen_kernel(
    const __hip_bfloat16* __restrict__ feats,  // [B,V,H,W,COUT] bf16
    const float* __restrict__ proj,            // [B,V,3,4]
    const float* __restrict__ coords,          // [B,NVOX,3]
    float* __restrict__ out)                   // [B,COUT,NVOX]
{
    const int tid = threadIdx.x;
    const int b   = blockIdx.y;
    const int vq  = tid & 3;                   // view owned by this lane
    const int n   = blockIdx.x*64 + (tid >> 2);

    const float* cp = coords + ((size_t)b*NVOX + n)*3;
    const float X = cp[0], Y = cp[1], Z = cp[2];

    const float LOG2E = 1.4426950408889634f;

    // single-view projection (per-lane; quad covers all 4 views)
    const float* P = proj + (size_t)(b*NV + vq)*12;
    const float wz = P[8]*X + P[9]*Y + P[10]*Z + P[11];
    const bool  vz = wz > 0.f;
    const float rz = __builtin_amdgcn_rcpf(wz);
    float px = (P[0]*X + P[1]*Y + P[2]*Z + P[3]) * rz * (95.f/96.f);
    float py = (P[4]*X + P[5]*Y + P[6]*Z + P[7]) * rz * (95.f/96.f);
    px = vz ? px : 0.f;  py = vz ? py : 0.f;
    px = fminf(fmaxf(px, -1.0e6f), 1.0e6f);
    py = fminf(fmaxf(py, -1.0e6f), 1.0e6f);
    const float fx0 = floorf(px), fy0 = floorf(py);
    const int x0 = (int)fx0, y0 = (int)fy0, x1 = x0+1, y1 = y0+1;
    const float wx1 = px - fx0, wx0 = 1.f - wx1;
    const float wy1 = py - fy0, wy0 = 1.f - wy1;
    const bool vx0 = (unsigned)x0 < (unsigned)IMG_W;
    const bool vx1 = (unsigned)x1 < (unsigned)IMG_W;
    const bool vy0 = (unsigned)y0 < (unsigned)IMG_H;
    const bool vy1 = (unsigned)y1 < (unsigned)IMG_H;
    const int cx0 = min(max(x0, 0), IMG_W-1), cx1 = min(max(x1, 0), IMG_W-1);
    const int cy0 = min(max(y0, 0), IMG_H-1), cy1 = min(max(y1, 0), IMG_H-1);
    const int base = ((b*NV + vq)*HW)*COUT*2;          // bytes
    int   off[4];
    float wgt[4];
    off[0] = base + (cy0*IMG_W + cx0)*(COUT*2);  wgt[0] = (vz & vx0 & vy0) ? wx0*wy0*LOG2E : 0.f;
    off[1] = base + (cy0*IMG_W + cx1)*(COUT*2);  wgt[1] = (vz & vx1 & vy0) ? wx1*wy0*LOG2E : 0.f;
    off[2] = base + (cy1*IMG_W + cx0)*(COUT*2);  wgt[2] = (vz & vx0 & vy1) ? wx0*wy1*LOG2E : 0.f;
    off[3] = base + (cy1*IMG_W + cx1)*(COUT*2);  wgt[3] = (vz & vx1 & vy1) ? wx1*wy1*LOG2E : 0.f;

    const char* fb = (const char*)feats;
    const size_t ob = (size_t)b*COUT*NVOX + n;
    const float LN2 = 0.6931471805599453f;

    uint4 t[4], tn[4];
    #pragma unroll
    for (int c = 0; c < 4; ++c)                 // prime chunk 0 (4 corners)
        t[c] = *(const uint4*)(fb + off[c]);

    #pragma unroll
    for (int ch0 = 0; ch0 < COUT; ch0 += 8) {
        if (ch0 + 8 < COUT) {
            #pragma unroll
            for (int c = 0; c < 4; ++c)         // prefetch next chunk
                tn[c] = *(const uint4*)(fb + off[c] + (ch0 + 8)*2);
        }

        f32x2 s2[4];
        #pragma unroll
        for (int c = 0; c < 4; ++c) {
            const float w = wgt[c];
            const f32x2 w2 = { w, w };
            const unsigned tu[4] = { t[c].x, t[c].y, t[c].z, t[c].w };
            #pragma unroll
            for (int k = 0; k < 4; ++k) {       // packed fma: 2 ch/instr
                f32x2 f2;
                f2.x = __uint_as_float(tu[k] << 16);
                f2.y = __uint_as_float(tu[k] & 0xffff0000u);
                if (c == 0) s2[k] = w2 * f2;
                else        s2[k] += w2 * f2;
            }
        }

        f32x2 A2[4], B2[4];
        #pragma unroll
        for (int k = 0; k < 4; ++k) {
            f32x2 e2;
            e2.x = fast_exp2(s2[k].x);          // wgt pre-scaled: 2^s' = e^s
            e2.y = fast_exp2(s2[k].y);
            A2[k] = e2;
            B2[k] = s2[k]*e2;
        }

        // quad butterfly: sum A,B over the 4 view-lanes
        #pragma unroll
        for (int m = 1; m <= 2; m <<= 1) {
            #pragma unroll
            for (int k = 0; k < 4; ++k) {
                A2[k].x += __shfl_xor(A2[k].x, m, 64);
                A2[k].y += __shfl_xor(A2[k].y, m, 64);
                B2[k].x += __shfl_xor(B2[k].x, m, 64);
                B2[k].y += __shfl_xor(B2[k].y, m, 64);
            }
        }

        // lane vq stores channels ch0+2vq, ch0+2vq+1 (static-index selects,
        // rule #20: no runtime array indexing)
        const f32x2 Alo = (vq & 1) ? A2[1] : A2[0];
        const f32x2 Ahi = (vq & 1) ? A2[3] : A2[2];
        const f32x2 Aq  = (vq & 2) ? Ahi : Alo;
        const f32x2 Blo = (vq & 1) ? B2[1] : B2[0];
        const f32x2 Bhi = (vq & 1) ? B2[3] : B2[2];
        const f32x2 Bq  = (vq & 2) ? Bhi : Blo;
        out[ob + (size_t)(ch0 + 2*vq    )*NVOX] = Bq.x * __builtin_amdgcn_rcpf(Aq.x) * LN2;
        out[ob + (size_t)(ch0 + 2*vq + 1)*NVOX] = Bq.y * __builtin_amdgcn_rcpf(Aq.y) * LN2;

        if (ch0 + 8 < COUT) {
            #pragma unroll
            for (int c = 0; c < 4; ++c) t[c] = tn[c];   // rotate
        }
    }
}

extern "C" void kernel_launch(void* const* d_in, const int* in_sizes, int n_in,
                              void* d_out, int out_size, void* d_ws, size_t ws_size,
                              hipStream_t stream)
{
    const float* features = (const float*)d_in[0];   // [2,4,256,96,96]
    const float* proj     = (const float*)d_in[1];   // [2,4,3,4]
    const float* coords   = (const float*)d_in[2];   // [2,64,64,64,3]
    const float* Wp       = (const float*)d_in[3];   // [32,256]
    const float* bp       = (const float*)d_in[4];   // [32]
    float* out = (float*)d_out;                      // [2,32,64,64,64]
    __hip_bfloat16* featsT = (__hip_bfloat16*)d_ws;  // [2,4,96,96,32] bf16 = 4.72 MB

    hipLaunchKernelGGL(conv1x1_kernel, dim3(HW/64, NB*NV), dim3(256), 0, stream,
                       features, Wp, bp, featsT);
    hipLaunchKernelGGL(volgen_kernel, dim3(NVOX/64, NB), dim3(256), 0, stream,
                       featsT, proj, coords, out);
}

// Round 14
// 178.048 us; speedup vs baseline: 1.7770x; 1.1733x over previous
//
#include <hip/hip_runtime.h>
#include <hip/hip_bf16.h>

#define CIN   256
#define COUT  32
#define IMG_H 96
#define IMG_W 96
#define HW    (IMG_H*IMG_W)
#define NB    2
#define NV    4
#define VSZ   64
#define NVOX  (VSZ*VSZ*VSZ)

typedef __attribute__((ext_vector_type(2))) float f32x2;

__device__ __forceinline__ float fast_exp2(float x) {
    float r;
    asm("v_exp_f32 %0, %1" : "=v"(r) : "v"(x));
    return r;
}

// Kernel 1 (FINAL = R6 verbatim): 1x1 conv -> channel-last bf16.
// 8 structural variants tried (R7-R16): VGPR dbuf x2 (100/109us), LDS
// staging w4 (122us), canonical global_load_lds GEMM w16 (189us),
// CIN-split (89us), K-split 512thr (null), float2+pkfma (null),
// LDS-weight broadcast (59us). Every axis -- MLP, occupancy, traffic,
// instr width, weight path, staging -- null or worse. 44.7us at VGPR 16,
// 18 waves/CU, ~10.5 B/cy/CU VMEM return is this op's source-level floor
// on gfx950. DO NOT TOUCH.
__global__ __launch_bounds__(256) void conv1x1_kernel(
    const float* __restrict__ features,   // [B,V,CIN,H,W] fp32
    const float* __restrict__ Wp,         // [COUT,CIN]
    const float* __restrict__ bp,         // [COUT]
    __hip_bfloat16* __restrict__ out)     // [B,V,H,W,COUT] bf16
{
    const int og   = __builtin_amdgcn_readfirstlane((threadIdx.x >> 6) & 3);
    const int lane = threadIdx.x & 63;
    const int bv   = blockIdx.y;
    const int px   = blockIdx.x*64 + lane;
    const float* f     = features + (size_t)bv*CIN*HW + px;
    const float* wbase = Wp + (size_t)og*8*CIN;     // uniform -> scalar base

    float acc[8];
    #pragma unroll
    for (int j = 0; j < 8; ++j) acc[j] = bp[og*8 + j];   // uniform -> s_load

    for (int cc = 0; cc < CIN; cc += 8) {
        float x[8];
        #pragma unroll
        for (int i = 0; i < 8; ++i)                  // 8 indep coalesced loads
            x[i] = f[(size_t)(cc + i)*HW];
        #pragma unroll
        for (int i = 0; i < 8; ++i) {
            #pragma unroll
            for (int j = 0; j < 8; ++j)              // v_fmac v, s, v
                acc[j] += x[i] * wbase[(size_t)j*CIN + cc + i];
        }
    }

    union { uint4 u4; __hip_bfloat16 h[8]; } pk;
    #pragma unroll
    for (int j = 0; j < 8; ++j) pk.h[j] = __float2bfloat16(acc[j]);
    *(uint4*)(out + ((size_t)(bv*HW + px))*COUT + og*8) = pk.u4;
}

// Kernel 2 (FINAL = R6 structure, best measured ~43us): voxel-per-lane,
// chunk-major, depth-1 view prefetch, exp2-folded weights.
// Refuted alternatives: frustum skip (R10, predicate never fires),
// depth-2 flat pipeline (R12, L2 thrash FETCH 5.6->52MB), cross-chunk
// prefetch (R11, neutral), view-per-lane quad split (R17, 73us: shuffle
// overhead + 4x threads on same gather stream). ~55% gather-stall on
// L2/L3-resident featsT at full MLP is the structure's floor.
__global__ __launch_bounds__(256, 4) void volgen_kernel(
    const __hip_bfloat16* __restrict__ feats,  // [B,V,H,W,COUT] bf16
    const float* __restrict__ proj,            // [B,V,3,4]
    const float* __restrict__ coords,          // [B,NVOX,3]
    float* __restrict__ out)                   // [B,COUT,NVOX]
{
    const int tid = threadIdx.x;
    const int b   = blockIdx.y;
    const int n   = blockIdx.x*256 + tid;

    const float* cp = coords + ((size_t)b*NVOX + n)*3;
    const float X = cp[0], Y = cp[1], Z = cp[2];

    const float LOG2E = 1.4426950408889634f;

    int   off[NV][4];                          // byte offsets into feats
    float wgt[NV][4];                          // bilinear weight * log2(e)
    #pragma unroll
    for (int v = 0; v < NV; ++v) {
        const float* P = proj + (size_t)(b*NV + v)*12;   // uniform -> scalar
        const float wz = P[8]*X + P[9]*Y + P[10]*Z + P[11];
        const bool  vz = wz > 0.f;
        const float rz = __builtin_amdgcn_rcpf(wz);
        float px = (P[0]*X + P[1]*Y + P[2]*Z + P[3]) * rz * (95.f/96.f);
        float py = (P[4]*X + P[5]*Y + P[6]*Z + P[7]) * rz * (95.f/96.f);
        px = vz ? px : 0.f;  py = vz ? py : 0.f;
        px = fminf(fmaxf(px, -1.0e6f), 1.0e6f);
        py = fminf(fmaxf(py, -1.0e6f), 1.0e6f);
        const float fx0 = floorf(px), fy0 = floorf(py);
        const int x0 = (int)fx0, y0 = (int)fy0, x1 = x0+1, y1 = y0+1;
        const float wx1 = px - fx0, wx0 = 1.f - wx1;
        const float wy1 = py - fy0, wy0 = 1.f - wy1;
        const bool vx0 = (unsigned)x0 < (unsigned)IMG_W;
        const bool vx1 = (unsigned)x1 < (unsigned)IMG_W;
        const bool vy0 = (unsigned)y0 < (unsigned)IMG_H;
        const bool vy1 = (unsigned)y1 < (unsigned)IMG_H;
        const int cx0 = min(max(x0, 0), IMG_W-1), cx1 = min(max(x1, 0), IMG_W-1);
        const int cy0 = min(max(y0, 0), IMG_H-1), cy1 = min(max(y1, 0), IMG_H-1);
        const int base = ((b*NV + v)*HW)*COUT*2;         // bytes, uniform
        off[v][0] = base + (cy0*IMG_W + cx0)*(COUT*2);  wgt[v][0] = (vz & vx0 & vy0) ? wx0*wy0*LOG2E : 0.f;
        off[v][1] = base + (cy0*IMG_W + cx1)*(COUT*2);  wgt[v][1] = (vz & vx1 & vy0) ? wx1*wy0*LOG2E : 0.f;
        off[v][2] = base + (cy1*IMG_W + cx0)*(COUT*2);  wgt[v][2] = (vz & vx0 & vy1) ? wx0*wy1*LOG2E : 0.f;
        off[v][3] = base + (cy1*IMG_W + cx1)*(COUT*2);  wgt[v][3] = (vz & vx1 & vy1) ? wx1*wy1*LOG2E : 0.f;
    }

    const char* fb = (const char*)feats;
    const size_t ob = (size_t)b*COUT*NVOX + n;
    const float LN2 = 0.6931471805599453f;

    for (int ch0 = 0; ch0 < COUT; ch0 += 8) {
        f32x2 A2[4], B2[4];
        uint4 t[4], tn[4];

        #pragma unroll
        for (int c = 0; c < 4; ++c)                     // prime the pipeline
            t[c] = *(const uint4*)(fb + off[0][c] + ch0*2);

        #pragma unroll
        for (int v = 0; v < NV; ++v) {
            if (v < NV-1) {
                #pragma unroll
                for (int c = 0; c < 4; ++c)             // prefetch next view
                    tn[c] = *(const uint4*)(fb + off[v+1][c] + ch0*2);
            }

            f32x2 s2[4];
            #pragma unroll
            for (int c = 0; c < 4; ++c) {
                const float w = wgt[v][c];
                const f32x2 w2 = { w, w };
                const unsigned tu[4] = { t[c].x, t[c].y, t[c].z, t[c].w };
                #pragma unroll
                for (int k = 0; k < 4; ++k) {           // packed fma: 2 ch/instr
                    f32x2 f2;
                    f2.x = __uint_as_float(tu[k] << 16);
                    f2.y = __uint_as_float(tu[k] & 0xffff0000u);
                    if (c == 0) s2[k] = w2 * f2;        // no zero-init
                    else        s2[k] += w2 * f2;
                }
            }

            #pragma unroll
            for (int k = 0; k < 4; ++k) {
                f32x2 e2;
                e2.x = fast_exp2(s2[k].x);              // wgt pre-scaled: 2^s' = e^s
                e2.y = fast_exp2(s2[k].y);
                if (v == 0) { A2[k] = e2;  B2[k] = s2[k]*e2; }
                else        { A2[k] += e2; B2[k] += s2[k]*e2; }
            }

            if (v < NV-1) {
                #pragma unroll
                for (int c = 0; c < 4; ++c) t[c] = tn[c];   // rotate
            }
        }

        #pragma unroll
        for (int k = 0; k < 4; ++k) {                   // coalesced stores
            out[ob + (size_t)(ch0 + 2*k    )*NVOX] = B2[k].x * __builtin_amdgcn_rcpf(A2[k].x) * LN2;
            out[ob + (size_t)(ch0 + 2*k + 1)*NVOX] = B2[k].y * __builtin_amdgcn_rcpf(A2[k].y) * LN2;
        }
    }
}

extern "C" void kernel_launch(void* const* d_in, const int* in_sizes, int n_in,
                              void* d_out, int out_size, void* d_ws, size_t ws_size,
                              hipStream_t stream)
{
    const float* features = (const float*)d_in[0];   // [2,4,256,96,96]
    const float* proj     = (const float*)d_in[1];   // [2,4,3,4]
    const float* coords   = (const float*)d_in[2];   // [2,64,64,64,3]
    const float* Wp       = (const float*)d_in[3];   // [32,256]
    const float* bp       = (const float*)d_in[4];   // [32]
    float* out = (float*)d_out;                      // [2,32,64,64,64]
    __hip_bfloat16* featsT = (__hip_bfloat16*)d_ws;  // [2,4,96,96,32] bf16 = 4.72 MB

    hipLaunchKernelGGL(conv1x1_kernel, dim3(HW/64, NB*NV), dim3(256), 0, stream,
                       features, Wp, bp, featsT);
    hipLaunchKernelGGL(volgen_kernel, dim3(NVOX/256, NB), dim3(256), 0, stream,
                       featsT, proj, coords, out);
}